// Round 2
// baseline (291.238 us; speedup 1.0000x reference)
//
#include <hip/hip_runtime.h>
#include <float.h>

// Problem constants (B=16, N=M=4096, fp32, 3-D points)
#define BATCH    16
#define NPTS     4096
#define TOTALP   (BATCH * NPTS)        // 65536 points per set
#define NQ       (2 * TOTALP)          // 131072 total query points (both dirs)
#define CHUNKS   4
#define CHUNKPTS (NPTS / CHUNKS)       // 1024 opposite points per partial block

// ---------------------------------------------------------------------------
// Pack kernel: xyz (3 floats) -> xyzw (float4) with w = 0.5*||p||^2.
// Also zeroes d_out (poisoned 0xAA before every timed launch).
// ---------------------------------------------------------------------------
__global__ __launch_bounds__(256) void pack_kernel(
    const float* __restrict__ xyz1, const float* __restrict__ xyz2,
    float4* __restrict__ p1, float4* __restrict__ p2,
    float* __restrict__ out)
{
    int i = blockIdx.x * 256 + threadIdx.x;
    if (i == 0) { out[0] = 0.0f; out[1] = 0.0f; }
    const float* src = (i < TOTALP) ? xyz1 : xyz2;
    float4*      dst = (i < TOTALP) ? p1   : p2;
    int j = (i < TOTALP) ? i : (i - TOTALP);
    float x = src[3 * j + 0];
    float y = src[3 * j + 1];
    float z = src[3 * j + 2];
    dst[j] = make_float4(x, y, z, 0.5f * (x * x + y * y + z * z));
}

// ---------------------------------------------------------------------------
// Partial kernel: 2048 blocks. blk = qg*4 + c.
//   qg in [0,512): which group of 256 query points (covers both directions)
//   c  in [0,4):   which quarter of the opposite set this block scans
// Each thread owns one query point in VGPRs; the opposite chunk streams on
// the scalar pipe (wave-uniform s_load). Inner: 3 FMA + (4 min3)/8 per pair.
//   t_m = w_m - x . p_m  (w = 0.5||p||^2);  partial[c][q] = min_m t_m
// ---------------------------------------------------------------------------
__global__ __launch_bounds__(256) void chamfer_partial_kernel(
    const float4* __restrict__ pack1, const float4* __restrict__ pack2,
    float* __restrict__ partial)
{
    const int blk = blockIdx.x;
    const int qg  = blk >> 2;
    const int c   = blk & 3;
    const int q   = (qg << 8) + threadIdx.x;   // 0..131071
    const int dir = q >> 16;                   // 0: set1->set2, 1: set2->set1
    const int qi  = q & (TOTALP - 1);
    const int b   = qi >> 12;                  // batch index

    const float4* __restrict__ ownp = (dir == 0 ? pack1 : pack2);
    const float4* __restrict__ opp  =
        (dir == 0 ? pack2 : pack1) + b * NPTS + c * CHUNKPTS;

    const float4 a = ownp[qi];
    const float nx = -a.x, ny = -a.y, nz = -a.z;

    float m0 = FLT_MAX, m1 = FLT_MAX;

    for (int m = 0; m < CHUNKPTS; m += 8) {
        float t[8];
#pragma unroll
        for (int u = 0; u < 8; ++u) {
            const float4 p = opp[m + u];        // wave-uniform -> s_load
            float s = fmaf(nz, p.z, p.w);
            s = fmaf(ny, p.y, s);
            s = fmaf(nx, p.x, s);
            t[u] = s;
        }
        // min3-shaped tree: 4 x v_min3_f32 per 8 points
        const float a0 = fminf(fminf(t[0], t[1]), t[2]);
        const float a1 = fminf(fminf(t[3], t[4]), t[5]);
        m0 = fminf(fminf(t[6], t[7]), m0);
        m1 = fminf(fminf(a0, a1), m1);
    }

    partial[c * NQ + q] = fminf(m0, m1);
}

// ---------------------------------------------------------------------------
// Final kernel: 512 blocks x 256. Per query: min of 4 partials, add ||x||^2,
// block-reduce sum, one atomicAdd per block. Each block is direction-uniform.
// ---------------------------------------------------------------------------
__global__ __launch_bounds__(256) void chamfer_final_kernel(
    const float4* __restrict__ pack1, const float4* __restrict__ pack2,
    const float* __restrict__ partial, float* __restrict__ out)
{
    const int q   = blockIdx.x * 256 + threadIdx.x;
    const int dir = q >> 16;
    const int qi  = q & (TOTALP - 1);

    const float w = (dir == 0 ? pack1 : pack2)[qi].w;
    const float m = fminf(fminf(partial[q],          partial[NQ + q]),
                          fminf(partial[2 * NQ + q], partial[3 * NQ + q]));
    float d = 2.0f * w + 2.0f * m;   // = min_m ||x - p_m||^2

    for (int off = 32; off > 0; off >>= 1)
        d += __shfl_down(d, off);

    __shared__ float wsum[4];
    const int lane = threadIdx.x & 63;
    const int wv   = threadIdx.x >> 6;
    if (lane == 0) wsum[wv] = d;
    __syncthreads();
    if (threadIdx.x == 0) {
        float s = wsum[0] + wsum[1] + wsum[2] + wsum[3];
        atomicAdd(&out[dir], s * (1.0f / (float)TOTALP));
    }
}

// ---------------------------------------------------------------------------
// Fallback: previous single-kernel version (2 waves/SIMD) if ws is small.
// ---------------------------------------------------------------------------
__global__ __launch_bounds__(256) void chamfer_kernel(
    const float4* __restrict__ pack1, const float4* __restrict__ pack2,
    float* __restrict__ out)
{
    const int blk = blockIdx.x;
    const int dir = blk >> 8;
    const int idx = blk & 255;
    const int b   = idx >> 4;
    const int n0  = (idx & 15) << 8;

    const float4* __restrict__ own = (dir == 0 ? pack1 : pack2) + b * NPTS;
    const float4* __restrict__ opp = (dir == 0 ? pack2 : pack1) + b * NPTS;

    const int n = n0 + threadIdx.x;
    const float4 a = own[n];
    const float nx = -a.x, ny = -a.y, nz = -a.z;

    float m0 = FLT_MAX, m1 = FLT_MAX;
    for (int m = 0; m < NPTS; m += 8) {
        float t[8];
#pragma unroll
        for (int u = 0; u < 8; ++u) {
            const float4 p = opp[m + u];
            float s = fmaf(nz, p.z, p.w);
            s = fmaf(ny, p.y, s);
            s = fmaf(nx, p.x, s);
            t[u] = s;
        }
        const float a0 = fminf(fminf(t[0], t[1]), t[2]);
        const float a1 = fminf(fminf(t[3], t[4]), t[5]);
        m0 = fminf(fminf(t[6], t[7]), m0);
        m1 = fminf(fminf(a0, a1), m1);
    }

    float d = 2.0f * a.w + 2.0f * fminf(m0, m1);
    for (int off = 32; off > 0; off >>= 1)
        d += __shfl_down(d, off);

    __shared__ float wsum[4];
    const int lane = threadIdx.x & 63;
    const int wv   = threadIdx.x >> 6;
    if (lane == 0) wsum[wv] = d;
    __syncthreads();
    if (threadIdx.x == 0) {
        float s = wsum[0] + wsum[1] + wsum[2] + wsum[3];
        atomicAdd(&out[dir], s * (1.0f / (float)TOTALP));
    }
}

// ---------------------------------------------------------------------------
extern "C" void kernel_launch(void* const* d_in, const int* in_sizes, int n_in,
                              void* d_out, int out_size, void* d_ws, size_t ws_size,
                              hipStream_t stream)
{
    const float* xyz1 = (const float*)d_in[0];
    const float* xyz2 = (const float*)d_in[1];
    float* out = (float*)d_out;

    const size_t packed_bytes  = (size_t)TOTALP * sizeof(float4);     // 1 MiB per set
    const size_t partial_bytes = (size_t)CHUNKS * NQ * sizeof(float); // 2 MiB

    if (ws_size >= 2 * packed_bytes + partial_bytes) {
        float4* p1      = (float4*)d_ws;
        float4* p2      = (float4*)((char*)d_ws + packed_bytes);
        float*  partial = (float*)((char*)d_ws + 2 * packed_bytes);

        pack_kernel<<<(2 * TOTALP) / 256, 256, 0, stream>>>(xyz1, xyz2, p1, p2, out);
        chamfer_partial_kernel<<<(NQ / 256) * CHUNKS, 256, 0, stream>>>(p1, p2, partial);
        chamfer_final_kernel<<<NQ / 256, 256, 0, stream>>>(p1, p2, partial, out);
    } else {
        float4* p1 = (float4*)d_ws;
        float4* p2 = (float4*)((char*)d_ws + packed_bytes);
        pack_kernel<<<(2 * TOTALP) / 256, 256, 0, stream>>>(xyz1, xyz2, p1, p2, out);
        chamfer_kernel<<<512, 256, 0, stream>>>(p1, p2, out);
    }
}

// Round 3
// 140.195 us; speedup vs baseline: 2.0774x; 2.0774x over previous
//
#include <hip/hip_runtime.h>
#include <float.h>

// Problem constants (B=16, N=M=4096, fp32, 3-D points)
#define BATCH    16
#define NPTS     4096
#define TOTALP   (BATCH * NPTS)        // 65536 points per set
#define NQ       (2 * TOTALP)          // 131072 query points (both dirs)
#define CHUNKS   4
#define CHUNKPTS (NPTS / CHUNKS)       // 1024 opposite points per partial block

// ---------------------------------------------------------------------------
// Pack kernel: xyz (3 floats) -> xyzw (float4) with w = 0.5*||p||^2.
// Also zeroes d_out (poisoned 0xAA before every timed launch).
// ---------------------------------------------------------------------------
__global__ __launch_bounds__(256) void pack_kernel(
    const float* __restrict__ xyz1, const float* __restrict__ xyz2,
    float4* __restrict__ p1, float4* __restrict__ p2,
    float* __restrict__ out)
{
    int i = blockIdx.x * 256 + threadIdx.x;
    if (i == 0) { out[0] = 0.0f; out[1] = 0.0f; }
    const float* src = (i < TOTALP) ? xyz1 : xyz2;
    float4*      dst = (i < TOTALP) ? p1   : p2;
    int j = (i < TOTALP) ? i : (i - TOTALP);
    float x = src[3 * j + 0];
    float y = src[3 * j + 1];
    float z = src[3 * j + 2];
    dst[j] = make_float4(x, y, z, 0.5f * (x * x + y * y + z * z));
}

// ---------------------------------------------------------------------------
// Partial kernel: 2048 blocks.
//   blk = dir*1024 + b*64 + qb*4 + c      (ALL selectors block-uniform!)
//     dir in [0,2): direction      b in [0,16): batch
//     qb  in [0,16): query group of 256 within the batch
//     c   in [0,4):  quarter of the opposite set this block scans
// The opposite-chunk pointer depends only on blockIdx.x -> wave-uniform ->
// compiler emits s_load_dwordx16 on the scalar pipe. Each thread owns one
// query point in VGPRs. Inner loop: 24 fma + 4 min3 per 8 pairs.
//   t_m = w_m - x . p_m  (w = 0.5||p||^2);  partial[c][q] = min_m t_m
// ---------------------------------------------------------------------------
__global__ __launch_bounds__(256) void chamfer_partial_kernel(
    const float4* __restrict__ pack1, const float4* __restrict__ pack2,
    float* __restrict__ partial)
{
    const int blk = blockIdx.x;
    const int c   = blk & 3;
    const int qb  = (blk >> 2) & 15;
    const int b   = (blk >> 6) & 15;
    const int dir = blk >> 10;                  // block-uniform

    const float4* __restrict__ ownp = (dir == 0 ? pack1 : pack2);
    const float4* __restrict__ opp  =
        (dir == 0 ? pack2 : pack1) + b * NPTS + c * CHUNKPTS;  // scalar pointer

    const int qi = (b << 12) + (qb << 8) + threadIdx.x;  // query idx within set
    const float4 a = ownp[qi];
    const float nx = -a.x, ny = -a.y, nz = -a.z;

    float m0 = FLT_MAX, m1 = FLT_MAX;

    for (int m = 0; m < CHUNKPTS; m += 8) {
        float t[8];
#pragma unroll
        for (int u = 0; u < 8; ++u) {
            const float4 p = opp[m + u];        // wave-uniform -> s_load
            float s = fmaf(nz, p.z, p.w);
            s = fmaf(ny, p.y, s);
            s = fmaf(nx, p.x, s);
            t[u] = s;
        }
        const float a0 = fminf(fminf(t[0], t[1]), t[2]);   // v_min3
        const float a1 = fminf(fminf(t[3], t[4]), t[5]);   // v_min3
        m0 = fminf(fminf(t[6], t[7]), m0);                 // v_min3
        m1 = fminf(fminf(a0, a1), m1);                     // v_min3
    }

    const int q = (dir << 16) + qi;             // global query index
    partial[c * NQ + q] = fminf(m0, m1);
}

// ---------------------------------------------------------------------------
// Final kernel: 512 blocks x 256. dir block-uniform. Per query: min of 4
// partials, add ||x||^2, block-reduce sum, one atomicAdd per block.
// ---------------------------------------------------------------------------
__global__ __launch_bounds__(256) void chamfer_final_kernel(
    const float4* __restrict__ pack1, const float4* __restrict__ pack2,
    const float* __restrict__ partial, float* __restrict__ out)
{
    const int dir = blockIdx.x >> 8;                       // block-uniform
    const int qi  = ((blockIdx.x & 255) << 8) + threadIdx.x;
    const int q   = (dir << 16) + qi;

    const float w = (dir == 0 ? pack1 : pack2)[qi].w;
    const float m = fminf(fminf(partial[q],          partial[NQ + q]),
                          fminf(partial[2 * NQ + q], partial[3 * NQ + q]));
    float d = 2.0f * w + 2.0f * m;   // = min_m ||x - p_m||^2

    for (int off = 32; off > 0; off >>= 1)
        d += __shfl_down(d, off);

    __shared__ float wsum[4];
    const int lane = threadIdx.x & 63;
    const int wv   = threadIdx.x >> 6;
    if (lane == 0) wsum[wv] = d;
    __syncthreads();
    if (threadIdx.x == 0) {
        float s = wsum[0] + wsum[1] + wsum[2] + wsum[3];
        atomicAdd(&out[dir], s * (1.0f / (float)TOTALP));
    }
}

// ---------------------------------------------------------------------------
// Fallback: Round-1 single-kernel version if ws is too small (not expected).
// ---------------------------------------------------------------------------
__global__ __launch_bounds__(256) void chamfer_kernel(
    const float4* __restrict__ pack1, const float4* __restrict__ pack2,
    float* __restrict__ out)
{
    const int blk = blockIdx.x;
    const int dir = blk >> 8;
    const int idx = blk & 255;
    const int b   = idx >> 4;
    const int n0  = (idx & 15) << 8;

    const float4* __restrict__ own = (dir == 0 ? pack1 : pack2) + b * NPTS;
    const float4* __restrict__ opp = (dir == 0 ? pack2 : pack1) + b * NPTS;

    const int n = n0 + threadIdx.x;
    const float4 a = own[n];
    const float nx = -a.x, ny = -a.y, nz = -a.z;

    float m0 = FLT_MAX, m1 = FLT_MAX;
    for (int m = 0; m < NPTS; m += 8) {
        float t[8];
#pragma unroll
        for (int u = 0; u < 8; ++u) {
            const float4 p = opp[m + u];
            float s = fmaf(nz, p.z, p.w);
            s = fmaf(ny, p.y, s);
            s = fmaf(nx, p.x, s);
            t[u] = s;
        }
        const float a0 = fminf(fminf(t[0], t[1]), t[2]);
        const float a1 = fminf(fminf(t[3], t[4]), t[5]);
        m0 = fminf(fminf(t[6], t[7]), m0);
        m1 = fminf(fminf(a0, a1), m1);
    }

    float d = 2.0f * a.w + 2.0f * fminf(m0, m1);
    for (int off = 32; off > 0; off >>= 1)
        d += __shfl_down(d, off);

    __shared__ float wsum[4];
    const int lane = threadIdx.x & 63;
    const int wv   = threadIdx.x >> 6;
    if (lane == 0) wsum[wv] = d;
    __syncthreads();
    if (threadIdx.x == 0) {
        float s = wsum[0] + wsum[1] + wsum[2] + wsum[3];
        atomicAdd(&out[dir], s * (1.0f / (float)TOTALP));
    }
}

// ---------------------------------------------------------------------------
extern "C" void kernel_launch(void* const* d_in, const int* in_sizes, int n_in,
                              void* d_out, int out_size, void* d_ws, size_t ws_size,
                              hipStream_t stream)
{
    const float* xyz1 = (const float*)d_in[0];
    const float* xyz2 = (const float*)d_in[1];
    float* out = (float*)d_out;

    const size_t packed_bytes  = (size_t)TOTALP * sizeof(float4);     // 1 MiB per set
    const size_t partial_bytes = (size_t)CHUNKS * NQ * sizeof(float); // 2 MiB

    if (ws_size >= 2 * packed_bytes + partial_bytes) {
        float4* p1      = (float4*)d_ws;
        float4* p2      = (float4*)((char*)d_ws + packed_bytes);
        float*  partial = (float*)((char*)d_ws + 2 * packed_bytes);

        pack_kernel<<<(2 * TOTALP) / 256, 256, 0, stream>>>(xyz1, xyz2, p1, p2, out);
        chamfer_partial_kernel<<<2048, 256, 0, stream>>>(p1, p2, partial);
        chamfer_final_kernel<<<NQ / 256, 256, 0, stream>>>(p1, p2, partial, out);
    } else {
        float4* p1 = (float4*)d_ws;
        float4* p2 = (float4*)((char*)d_ws + packed_bytes);
        pack_kernel<<<(2 * TOTALP) / 256, 256, 0, stream>>>(xyz1, xyz2, p1, p2, out);
        chamfer_kernel<<<512, 256, 0, stream>>>(p1, p2, out);
    }
}

// Round 4
// 123.861 us; speedup vs baseline: 2.3513x; 1.1319x over previous
//
#include <hip/hip_runtime.h>
#include <float.h>

// Problem constants (B=16, N=M=4096, fp32, 3-D points)
#define BATCH    16
#define NPTS     4096
#define TOTALP   (BATCH * NPTS)        // 65536 points per set
#define NQ       (2 * TOTALP)          // 131072 query points (both dirs)

// ---------------------------------------------------------------------------
// Pack kernel: xyz (3 floats) -> xyzw (float4) with w = 0.5*||p||^2.
// Also zeroes d_out (poisoned 0xAA before every timed launch).
// ---------------------------------------------------------------------------
__global__ __launch_bounds__(256) void pack_kernel(
    const float* __restrict__ xyz1, const float* __restrict__ xyz2,
    float4* __restrict__ p1, float4* __restrict__ p2,
    float* __restrict__ out)
{
    int i = blockIdx.x * 256 + threadIdx.x;
    if (i == 0) { out[0] = 0.0f; out[1] = 0.0f; }
    const float* src = (i < TOTALP) ? xyz1 : xyz2;
    float4*      dst = (i < TOTALP) ? p1   : p2;
    int j = (i < TOTALP) ? i : (i - TOTALP);
    float x = src[3 * j + 0];
    float y = src[3 * j + 1];
    float z = src[3 * j + 2];
    dst[j] = make_float4(x, y, z, 0.5f * (x * x + y * y + z * z));
}

// ---------------------------------------------------------------------------
// 8-point uniform buffer. Loaded from a wave-uniform address -> the compiler
// keeps it in SGPRs (s_load_dwordx16 x2 on the scalar pipe).
// ---------------------------------------------------------------------------
struct P8 { float4 p[8]; };

__device__ __forceinline__ P8 load8(const float4* __restrict__ s)
{
    P8 r;
#pragma unroll
    for (int u = 0; u < 8; ++u) r.p[u] = s[u];
    return r;
}

// Accumulate 8 opposite points against 2 query points.
// Per point: 1 v_mov (p.w->VGPR, shared by both queries) + 6 fma.
// Per 8 points: 8 v_min3 (4 per query). Total 64 VALU / 16 pairs = 4.0/pair.
__device__ __forceinline__ void accum8(
    const P8& bf,
    float nx0, float ny0, float nz0,
    float nx1, float ny1, float nz1,
    float& m0a, float& m0b, float& m1a, float& m1b)
{
    float t0[8], t1[8];
#pragma unroll
    for (int u = 0; u < 8; ++u) {
        const float4 p = bf.p[u];
        float s0 = fmaf(nz0, p.z, p.w);
        s0 = fmaf(ny0, p.y, s0);
        s0 = fmaf(nx0, p.x, s0);
        float s1 = fmaf(nz1, p.z, p.w);
        s1 = fmaf(ny1, p.y, s1);
        s1 = fmaf(nx1, p.x, s1);
        t0[u] = s0;
        t1[u] = s1;
    }
    {   // v_min3-shaped trees
        const float a0 = fminf(fminf(t0[0], t0[1]), t0[2]);
        const float a1 = fminf(fminf(t0[3], t0[4]), t0[5]);
        m0a = fminf(fminf(t0[6], t0[7]), m0a);
        m0b = fminf(fminf(a0, a1), m0b);
    }
    {
        const float a0 = fminf(fminf(t1[0], t1[1]), t1[2]);
        const float a1 = fminf(fminf(t1[3], t1[4]), t1[5]);
        m1a = fminf(fminf(t1[6], t1[7]), m1a);
        m1b = fminf(fminf(a0, a1), m1b);
    }
}

// ---------------------------------------------------------------------------
// Partial kernel, templated on CHUNKS (opposite-set split factor).
//   blk = ((dir*16 + b)*8 + qb)*CHUNKS + c     (ALL selectors block-uniform)
//   Each thread owns 2 query points: qi0 = b*4096 + qb*512 + tid, qi1 = qi0+256.
//   Opposite chunk (NPTS/CHUNKS points) streams on the scalar pipe with a
//   ping-pong pair of 8-point SGPR buffers (s_loads issued one buffer ahead).
//   t_m = w_m - x . p_m  (w = 0.5||p||^2);  partial[c][q] = min_m t_m
// ---------------------------------------------------------------------------
template <int CHUNKS>
__global__ __launch_bounds__(256) void chamfer_partial_kernel(
    const float4* __restrict__ pack1, const float4* __restrict__ pack2,
    float* __restrict__ partial)
{
    constexpr int L = NPTS / CHUNKS;            // chunk length (power of 2)

    const int blk = blockIdx.x;
    const int c   = blk % CHUNKS;
    const int qb  = (blk / CHUNKS) & 7;
    const int b   = (blk / (CHUNKS * 8)) & 15;
    const int dir = blk / (CHUNKS * 8 * 16);    // block-uniform

    const float4* __restrict__ ownp = (dir == 0 ? pack1 : pack2);
    const float4* __restrict__ opp  =
        (dir == 0 ? pack2 : pack1) + b * NPTS + c * L;   // scalar pointer

    const int qi0 = (b << 12) + (qb << 9) + threadIdx.x; // query idx in set
    const float4 a0 = ownp[qi0];
    const float4 a1 = ownp[qi0 + 256];
    const float nx0 = -a0.x, ny0 = -a0.y, nz0 = -a0.z;
    const float nx1 = -a1.x, ny1 = -a1.y, nz1 = -a1.z;

    float m0a = FLT_MAX, m0b = FLT_MAX, m1a = FLT_MAX, m1b = FLT_MAX;

    P8 A = load8(opp);
    for (int m = 0; m < L; m += 16) {
        P8 B = load8(opp + m + 8);
        accum8(A, nx0, ny0, nz0, nx1, ny1, nz1, m0a, m0b, m1a, m1b);
        A = load8(opp + ((m + 16) & (L - 1)));  // wrap keeps flow branchless
        accum8(B, nx0, ny0, nz0, nx1, ny1, nz1, m0a, m0b, m1a, m1b);
    }

    const int q = (dir << 16) + qi0;            // global query index
    partial[c * NQ + q]       = fminf(m0a, m0b);
    partial[c * NQ + q + 256] = fminf(m1a, m1b);
}

// ---------------------------------------------------------------------------
// Final kernel: 512 blocks x 256, dir block-uniform. Per query: min of
// CHUNKS partials, add ||x||^2, block-reduce sum, one atomicAdd per block.
// ---------------------------------------------------------------------------
template <int CHUNKS>
__global__ __launch_bounds__(256) void chamfer_final_kernel(
    const float4* __restrict__ pack1, const float4* __restrict__ pack2,
    const float* __restrict__ partial, float* __restrict__ out)
{
    const int dir = blockIdx.x >> 8;                       // block-uniform
    const int qi  = ((blockIdx.x & 255) << 8) + threadIdx.x;
    const int q   = (dir << 16) + qi;

    const float w = (dir == 0 ? pack1 : pack2)[qi].w;
    float m = partial[q];
#pragma unroll
    for (int cc = 1; cc < CHUNKS; ++cc)
        m = fminf(m, partial[cc * NQ + q]);
    float d = 2.0f * w + 2.0f * m;   // = min_m ||x - p_m||^2

    for (int off = 32; off > 0; off >>= 1)
        d += __shfl_down(d, off);

    __shared__ float wsum[4];
    const int lane = threadIdx.x & 63;
    const int wv   = threadIdx.x >> 6;
    if (lane == 0) wsum[wv] = d;
    __syncthreads();
    if (threadIdx.x == 0) {
        float s = wsum[0] + wsum[1] + wsum[2] + wsum[3];
        atomicAdd(&out[dir], s * (1.0f / (float)TOTALP));
    }
}

// ---------------------------------------------------------------------------
// Fallback: Round-1 single-kernel version if ws is too small (not expected).
// ---------------------------------------------------------------------------
__global__ __launch_bounds__(256) void chamfer_kernel(
    const float4* __restrict__ pack1, const float4* __restrict__ pack2,
    float* __restrict__ out)
{
    const int blk = blockIdx.x;
    const int dir = blk >> 8;
    const int idx = blk & 255;
    const int b   = idx >> 4;
    const int n0  = (idx & 15) << 8;

    const float4* __restrict__ own = (dir == 0 ? pack1 : pack2) + b * NPTS;
    const float4* __restrict__ opp = (dir == 0 ? pack2 : pack1) + b * NPTS;

    const int n = n0 + threadIdx.x;
    const float4 a = own[n];
    const float nx = -a.x, ny = -a.y, nz = -a.z;

    float m0 = FLT_MAX, m1 = FLT_MAX;
    for (int m = 0; m < NPTS; m += 8) {
        float t[8];
#pragma unroll
        for (int u = 0; u < 8; ++u) {
            const float4 p = opp[m + u];
            float s = fmaf(nz, p.z, p.w);
            s = fmaf(ny, p.y, s);
            s = fmaf(nx, p.x, s);
            t[u] = s;
        }
        const float a0 = fminf(fminf(t[0], t[1]), t[2]);
        const float a1 = fminf(fminf(t[3], t[4]), t[5]);
        m0 = fminf(fminf(t[6], t[7]), m0);
        m1 = fminf(fminf(a0, a1), m1);
    }

    float d = 2.0f * a.w + 2.0f * fminf(m0, m1);
    for (int off = 32; off > 0; off >>= 1)
        d += __shfl_down(d, off);

    __shared__ float wsum[4];
    const int lane = threadIdx.x & 63;
    const int wv   = threadIdx.x >> 6;
    if (lane == 0) wsum[wv] = d;
    __syncthreads();
    if (threadIdx.x == 0) {
        float s = wsum[0] + wsum[1] + wsum[2] + wsum[3];
        atomicAdd(&out[dir], s * (1.0f / (float)TOTALP));
    }
}

// ---------------------------------------------------------------------------
extern "C" void kernel_launch(void* const* d_in, const int* in_sizes, int n_in,
                              void* d_out, int out_size, void* d_ws, size_t ws_size,
                              hipStream_t stream)
{
    const float* xyz1 = (const float*)d_in[0];
    const float* xyz2 = (const float*)d_in[1];
    float* out = (float*)d_out;

    const size_t packed_bytes = (size_t)TOTALP * sizeof(float4);  // 1 MiB per set

    float4* p1      = (float4*)d_ws;
    float4* p2      = (float4*)((char*)d_ws + packed_bytes);
    float*  partial = (float*)((char*)d_ws + 2 * packed_bytes);

    const size_t part8 = (size_t)8 * NQ * sizeof(float);  // 4 MiB
    const size_t part4 = (size_t)4 * NQ * sizeof(float);  // 2 MiB

    if (ws_size >= 2 * packed_bytes + part8) {
        // 2048 blocks -> 8 blocks/CU, 100% nominal occupancy
        pack_kernel<<<(2 * TOTALP) / 256, 256, 0, stream>>>(xyz1, xyz2, p1, p2, out);
        chamfer_partial_kernel<8><<<2 * 16 * 8 * 8, 256, 0, stream>>>(p1, p2, partial);
        chamfer_final_kernel<8><<<NQ / 256, 256, 0, stream>>>(p1, p2, partial, out);
    } else if (ws_size >= 2 * packed_bytes + part4) {
        pack_kernel<<<(2 * TOTALP) / 256, 256, 0, stream>>>(xyz1, xyz2, p1, p2, out);
        chamfer_partial_kernel<4><<<2 * 16 * 8 * 4, 256, 0, stream>>>(p1, p2, partial);
        chamfer_final_kernel<4><<<NQ / 256, 256, 0, stream>>>(p1, p2, partial, out);
    } else {
        pack_kernel<<<(2 * TOTALP) / 256, 256, 0, stream>>>(xyz1, xyz2, p1, p2, out);
        chamfer_kernel<<<512, 256, 0, stream>>>(p1, p2, out);
    }
}

// Round 5
// 104.870 us; speedup vs baseline: 2.7771x; 1.1811x over previous
//
#include <hip/hip_runtime.h>
#include <float.h>

// Problem constants (B=16, N=M=4096, fp32, 3-D points)
#define BATCH    16
#define NPTS     4096
#define TOTALP   (BATCH * NPTS)        // 65536 points per set
#define NQ       (2 * TOTALP)          // 131072 query points (both dirs)

// ---------------------------------------------------------------------------
// Partial kernel. Q=4 queries/thread, opposite chunk staged in LDS.
//   blk = (((dir*16 + b)*4 + qg)*CHUNKS + c        (ALL selectors uniform)
//     dir in [0,2), b in [0,16) batch, qg in [0,4): group of 1024 queries,
//     c in [0,CHUNKS): chunk of the opposite set (L = NPTS/CHUNKS points).
//   Staging: threads cooperatively read raw xyz, compute w = 0.5*||p||^2,
//   write float4 tiles to LDS. Hot loop: wave-uniform ds_read_b128 =
//   broadcast (conflict-free, in-order -> compiler pipelines via lgkmcnt(N)).
//   t_m = w_m - x.p_m ;  partial[c][q] = min_m t_m  (d = ||x||^2 + 2*min t)
// Block 0 also zeroes d_out (poisoned 0xAA before every timed launch).
// ---------------------------------------------------------------------------
template <int CHUNKS>
__global__ __launch_bounds__(256) void chamfer_partial_lds(
    const float* __restrict__ xyz1, const float* __restrict__ xyz2,
    float* __restrict__ partial, float* __restrict__ out)
{
    constexpr int L = NPTS / CHUNKS;           // chunk length (power of 2)
    __shared__ float4 tile[L];

    const int blk = blockIdx.x;
    const int c   = blk % CHUNKS;
    const int qg  = (blk / CHUNKS) & 3;
    const int b   = (blk / (CHUNKS * 4)) & 15;
    const int dir = blk / (CHUNKS * 64);       // block-uniform

    if (blk == 0 && threadIdx.x == 0) { out[0] = 0.0f; out[1] = 0.0f; }

    // ---- stage chunk into LDS (per-lane coalesced-ish VMEM reads) ----
    const float* __restrict__ opp =
        (dir == 0 ? xyz2 : xyz1) + (size_t)(b * NPTS + c * L) * 3;
    for (int i = threadIdx.x; i < L; i += 256) {
        const float px = opp[3 * i + 0];
        const float py = opp[3 * i + 1];
        const float pz = opp[3 * i + 2];
        tile[i] = make_float4(px, py, pz, 0.5f * (px * px + py * py + pz * pz));
    }

    // ---- load 4 query points (per-lane VMEM) ----
    const float* __restrict__ ownp =
        (dir == 0 ? xyz1 : xyz2) + (size_t)b * NPTS * 3;
    const int q0 = (qg << 10) + threadIdx.x;   // local query idx; +256*j
    float nx[4], ny[4], nz[4];
#pragma unroll
    for (int j = 0; j < 4; ++j) {
        const int qi = q0 + (j << 8);
        nx[j] = -ownp[3 * qi + 0];
        ny[j] = -ownp[3 * qi + 1];
        nz[j] = -ownp[3 * qi + 2];
    }

    __syncthreads();

    // ---- hot loop: 8 uniform ds_read_b128 + 96 fma + 16 min3 per step ----
    float mA[4], mB[4];
#pragma unroll
    for (int j = 0; j < 4; ++j) { mA[j] = FLT_MAX; mB[j] = FLT_MAX; }

    for (int m = 0; m < L; m += 8) {
        float4 P[8];
#pragma unroll
        for (int u = 0; u < 8; ++u) P[u] = tile[m + u];   // broadcast reads

        float t[4][8];
#pragma unroll
        for (int u = 0; u < 8; ++u) {
            const float4 p = P[u];
#pragma unroll
            for (int j = 0; j < 4; ++j) {
                float s = fmaf(nz[j], p.z, p.w);
                s = fmaf(ny[j], p.y, s);
                s = fmaf(nx[j], p.x, s);
                t[j][u] = s;
            }
        }
#pragma unroll
        for (int j = 0; j < 4; ++j) {       // v_min3-shaped trees (4 per j)
            const float a0 = fminf(fminf(t[j][0], t[j][1]), t[j][2]);
            const float a1 = fminf(fminf(t[j][3], t[j][4]), t[j][5]);
            mA[j] = fminf(fminf(t[j][6], t[j][7]), mA[j]);
            mB[j] = fminf(fminf(a0, a1), mB[j]);
        }
    }

    const int qbase = (dir << 16) + (b << 12) + q0;   // global query index
#pragma unroll
    for (int j = 0; j < 4; ++j)
        partial[(size_t)c * NQ + qbase + (j << 8)] = fminf(mA[j], mB[j]);
}

// ---------------------------------------------------------------------------
// Final kernel: 512 blocks x 256, dir block-uniform. Per query: min of
// CHUNKS partials, add ||x||^2, block-reduce sum, one atomicAdd per block.
// ---------------------------------------------------------------------------
template <int CHUNKS>
__global__ __launch_bounds__(256) void chamfer_final_kernel(
    const float* __restrict__ xyz1, const float* __restrict__ xyz2,
    const float* __restrict__ partial, float* __restrict__ out)
{
    const int dir = blockIdx.x >> 8;                       // block-uniform
    const int qi  = ((blockIdx.x & 255) << 8) + threadIdx.x;
    const int q   = (dir << 16) + qi;

    const float* __restrict__ ownp = (dir == 0 ? xyz1 : xyz2);
    const float x = ownp[3 * qi + 0];
    const float y = ownp[3 * qi + 1];
    const float z = ownp[3 * qi + 2];

    float m = partial[q];
#pragma unroll
    for (int cc = 1; cc < CHUNKS; ++cc)
        m = fminf(m, partial[(size_t)cc * NQ + q]);

    float d = (x * x + y * y + z * z) + 2.0f * m;   // = min_m ||x - p_m||^2

    for (int off = 32; off > 0; off >>= 1)
        d += __shfl_down(d, off);

    __shared__ float wsum[4];
    const int lane = threadIdx.x & 63;
    const int wv   = threadIdx.x >> 6;
    if (lane == 0) wsum[wv] = d;
    __syncthreads();
    if (threadIdx.x == 0) {
        float s = wsum[0] + wsum[1] + wsum[2] + wsum[3];
        atomicAdd(&out[dir], s * (1.0f / (float)TOTALP));
    }
}

// ---------------------------------------------------------------------------
// Fallback for tiny workspace: direct 7-op kernel, no ws needed.
// ---------------------------------------------------------------------------
__global__ void zero_out_kernel(float* __restrict__ out)
{
    if (threadIdx.x == 0) { out[0] = 0.0f; out[1] = 0.0f; }
}

__global__ __launch_bounds__(256) void chamfer_raw_kernel(
    const float* __restrict__ xyz1, const float* __restrict__ xyz2,
    float* __restrict__ out)
{
    const int blk = blockIdx.x;
    const int dir = blk >> 8;
    const int idx = blk & 255;
    const int b   = idx >> 4;
    const int n0  = (idx & 15) << 8;

    const float* __restrict__ own = (dir == 0 ? xyz1 : xyz2) + (size_t)b * NPTS * 3;
    const float* __restrict__ opp = (dir == 0 ? xyz2 : xyz1) + (size_t)b * NPTS * 3;

    const int n = n0 + threadIdx.x;
    const float ax = own[3 * n + 0];
    const float ay = own[3 * n + 1];
    const float az = own[3 * n + 2];

    float best = FLT_MAX;
    for (int m = 0; m < NPTS; m += 4) {
#pragma unroll
        for (int u = 0; u < 4; ++u) {
            const float px = opp[3 * (m + u) + 0];
            const float py = opp[3 * (m + u) + 1];
            const float pz = opp[3 * (m + u) + 2];
            const float dx = px - ax, dy = py - ay, dz = pz - az;
            float d = dx * dx;
            d = fmaf(dy, dy, d);
            d = fmaf(dz, dz, d);
            best = fminf(best, d);
        }
    }

    float d = best;
    for (int off = 32; off > 0; off >>= 1)
        d += __shfl_down(d, off);

    __shared__ float wsum[4];
    const int lane = threadIdx.x & 63;
    const int wv   = threadIdx.x >> 6;
    if (lane == 0) wsum[wv] = d;
    __syncthreads();
    if (threadIdx.x == 0) {
        float s = wsum[0] + wsum[1] + wsum[2] + wsum[3];
        atomicAdd(&out[dir], s * (1.0f / (float)TOTALP));
    }
}

// ---------------------------------------------------------------------------
extern "C" void kernel_launch(void* const* d_in, const int* in_sizes, int n_in,
                              void* d_out, int out_size, void* d_ws, size_t ws_size,
                              hipStream_t stream)
{
    const float* xyz1 = (const float*)d_in[0];
    const float* xyz2 = (const float*)d_in[1];
    float* out = (float*)d_out;
    float* partial = (float*)d_ws;

    const size_t part16 = (size_t)16 * NQ * sizeof(float);  // 8 MiB
    const size_t part8  = (size_t)8  * NQ * sizeof(float);  // 4 MiB
    const size_t part4  = (size_t)4  * NQ * sizeof(float);  // 2 MiB

    if (ws_size >= part16) {
        // 2048 blocks = 8 blocks/CU
        chamfer_partial_lds<16><<<2 * 16 * 4 * 16, 256, 0, stream>>>(xyz1, xyz2, partial, out);
        chamfer_final_kernel<16><<<NQ / 256, 256, 0, stream>>>(xyz1, xyz2, partial, out);
    } else if (ws_size >= part8) {
        // 1024 blocks = 4 blocks/CU
        chamfer_partial_lds<8><<<2 * 16 * 4 * 8, 256, 0, stream>>>(xyz1, xyz2, partial, out);
        chamfer_final_kernel<8><<<NQ / 256, 256, 0, stream>>>(xyz1, xyz2, partial, out);
    } else if (ws_size >= part4) {
        chamfer_partial_lds<4><<<2 * 16 * 4 * 4, 256, 0, stream>>>(xyz1, xyz2, partial, out);
        chamfer_final_kernel<4><<<NQ / 256, 256, 0, stream>>>(xyz1, xyz2, partial, out);
    } else {
        zero_out_kernel<<<1, 64, 0, stream>>>(out);
        chamfer_raw_kernel<<<512, 256, 0, stream>>>(xyz1, xyz2, out);
    }
}